// Round 12
// baseline (131.720 us; speedup 1.0000x reference)
//
#include <hip/hip_runtime.h>
#include <math.h>

#define Ddim 384
#define D4 96                      // Ddim/4
#define NUM_ITEMS 16384
#define NUM_CLUSTERS 256
#define MCS 128                    // MAX_CLUSTER_SIZE
#define NEG_INF_F (-1e9f)
#define NTOK 4096
#define TPB 16                     // tokens per compute block
#define NCB (NTOK / TPB)           // 256 compute blocks
#define NFB 512                    // fill blocks

__device__ __forceinline__ float dot4(const float4& a, const float4& b) {
    return a.x * b.x + a.y * b.y + a.z * b.z + a.w * b.w;
}

// One grid, 768 blocks x 512 threads. bid%3!=2 -> fill; bid%3==2 -> compute.
// Compute block: 16 tokens, 8 waves, each wave owns 2 tokens END-TO-END:
// cluster logits over ALL 256 clusters (hf[2][6]=48 VGPR stays register-
// resident under the 128-VGPR cap), softmax+argmax, then member gather
// reusing the SAME hf fragments (16-lane D-split), 64-slot exact softmax.
// R11 counters showed VGPR_Count=76 < the 96 needed by hf[4][6] -> h was
// rematerialized from global every iteration (12% VALU, latency-bound).
__global__ __launch_bounds__(512, 2) void hs_fused(
    const float* __restrict__ hidden,
    const float* __restrict__ item_emb,
    const float* __restrict__ cluster_emb,
    const float* __restrict__ item_mask,
    const int*   __restrict__ targets,
    const int*   __restrict__ cluster_assign,
    const int*   __restrict__ cluster_idx,
    const int*   __restrict__ in_cluster_id,
    float* __restrict__ dummy_out,
    float* __restrict__ ws)
{
    const int bid = blockIdx.x;
    const int tid = threadIdx.x;

    if (bid % 3 != 2) {
        // ---- fill: grid-strided plain stores; 512 blocks cover 268 MB ----
        const int fid = (bid / 3) * 2 + (bid % 3);          // 0..511
        float4 z; z.x = z.y = z.z = z.w = 0.f;
        float4* o4 = reinterpret_cast<float4*>(dummy_out)
                     + (size_t)fid * 512 + tid;
        #pragma unroll 8
        for (int i = 0; i < 64; ++i)
            o4[(size_t)i * (NFB * 512)] = z;                // 4 MB window/iter
        return;
    }

    const int cb   = bid / 3;              // 0..255
    const int t0   = cb * TPB;
    const int lane = tid & 63;
    const int wave = tid >> 6;             // 0..7 -> tokens t0+2w, t0+2w+1
    const int q    = lane >> 4;            // 4-cluster / 4-row subgroup
    const int r    = lane & 15;            // 16-lane D-split

    __shared__ float clog[TPB][NUM_CLUSTERS];   // 16 KB (wave-private rows)
    __shared__ float mlog[TPB][64];             // 4 KB

    const int tw = t0 + wave * 2;
    const float4* h4 = reinterpret_cast<const float4*>(hidden);
    float4 hf[2][6];
    #pragma unroll
    for (int j = 0; j < 2; ++j)
        #pragma unroll
        for (int i = 0; i < 6; ++i)
            hf[j][i] = h4[(size_t)(tw + j) * D4 + i * 16 + r];

    // ---- cluster logits: 64 iters x 4 clusters x 2 tokens ----
    const float4* ce4 = reinterpret_cast<const float4*>(cluster_emb);
    #pragma unroll 2
    for (int it = 0; it < 64; ++it) {
        const int c = it * 4 + q;
        float4 ce[6];
        #pragma unroll
        for (int i = 0; i < 6; ++i) ce[i] = ce4[(size_t)c * D4 + i * 16 + r];
        float a0 = 0.f, a1 = 0.f;
        #pragma unroll
        for (int i = 0; i < 6; ++i) {
            a0 += dot4(ce[i], hf[0][i]);
            a1 += dot4(ce[i], hf[1][i]);
        }
        // payload fold: bit3 selects token, bits 2..0 fold the 8-lane half
        const bool hi8 = (r & 8) != 0;
        float u  = hi8 ? a1 : a0;
        float uS = hi8 ? a0 : a1;
        u += __shfl_xor(uS, 8);
        u += __shfl_xor(u, 4);
        u += __shfl_xor(u, 2);
        u += __shfl_xor(u, 1);
        if ((r & 7) == 0)                   // r==0 -> token0, r==8 -> token1
            clog[wave * 2 + ((r >> 3) & 1)][c] = u;
    }
    __syncthreads();   // cheap safety barrier (all waves uniform)

    // ---- per wave: finish its 2 tokens ----
    const float4* ie4 = reinterpret_cast<const float4*>(item_emb);
    #pragma unroll
    for (int p = 0; p < 2; ++p) {
        const int t   = wave * 2 + p;
        const int gt  = t0 + t;
        const int tgt  = targets[gt];
        const int tc   = cluster_assign[tgt];
        const int tpos = in_cluster_id[tgt];
        const float msk = item_mask[gt];

        // cluster softmax + argmax (first-index tiebreak)
        const float v0 = clog[t][lane];
        const float v1 = clog[t][lane + 64];
        const float v2 = clog[t][lane + 128];
        const float v3 = clog[t][lane + 192];
        float bv = v0; int bi = lane;
        if (v1 > bv) { bv = v1; bi = lane + 64;  }
        if (v2 > bv) { bv = v2; bi = lane + 128; }
        if (v3 > bv) { bv = v3; bi = lane + 192; }
        #pragma unroll
        for (int m = 32; m > 0; m >>= 1) {
            const float ov = __shfl_xor(bv, m);
            const int   oi = __shfl_xor(bi, m);
            if (ov > bv || (ov == bv && oi < bi)) { bv = ov; bi = oi; }
        }
        float e = expf(v0 - bv) + expf(v1 - bv) + expf(v2 - bv) + expf(v3 - bv);
        #pragma unroll
        for (int m = 32; m > 0; m >>= 1) e += __shfl_xor(e, m);
        const float lse = bv + logf(e);
        const float tlpc = clog[t][tc] - lse;

        // ---- member: reuse hf[p] (16-lane split), 4 rows/iter, 16 iters ----
        // slots 0..63 of any cluster are always valid (id = tc + 256*slot).
        const int* crow = cluster_idx + (size_t)tc * MCS;
        #pragma unroll 2
        for (int it = 0; it < 16; ++it) {
            const int id = crow[it * 4 + q];
            const float4* ir = ie4 + (size_t)id * D4;
            float pa = 0.f;
            #pragma unroll
            for (int i = 0; i < 6; ++i) pa += dot4(ir[i * 16 + r], hf[p][i]);
            pa += __shfl_xor(pa, 8);
            pa += __shfl_xor(pa, 4);
            pa += __shfl_xor(pa, 2);
            pa += __shfl_xor(pa, 1);
            if (r == 0) mlog[t][it * 4 + q] = pa;
        }
        // wave-local exact softmax over the 64 valid slots
        const float w0 = mlog[t][lane];
        float mx = w0;
        #pragma unroll
        for (int m = 32; m > 0; m >>= 1) mx = fmaxf(mx, __shfl_xor(mx, m));
        float e2 = expf(w0 - mx);
        #pragma unroll
        for (int m = 32; m > 0; m >>= 1) e2 += __shfl_xor(e2, m);
        const float tlpi = mlog[t][tpos] - (mx + logf(e2));

        if (lane == 0) {
            ws[NTOK + gt]     = msk;
            ws[2 * NTOK + gt] = tlpc;
            ws[3 * NTOK + gt] = tlpi;
            ws[4 * NTOK + gt] = (bi == tc) ? 1.f : 0.f;
        }
    }
}

// ---------- deterministic final reduction ----------
__global__ __launch_bounds__(1024) void hs_final(
    const float* __restrict__ ws, float* __restrict__ out)
{
    __shared__ double red[5][1024];
    const int tid = threadIdx.x;
    double a0 = 0, a1 = 0, a2 = 0, a3 = 0, a4 = 0;
    for (int i = tid; i < NTOK; i += 1024) {
        const float msk  = ws[NTOK + i];
        const float tlpc = ws[2 * NTOK + i];
        const float tlpi = ws[3 * NTOK + i];
        a0 += (double)(-(tlpc + tlpi) * msk);
        a1 += (double)msk;
        a2 += (double)tlpc;
        a3 += (double)tlpi;
        a4 += (double)ws[4 * NTOK + i];
    }
    red[0][tid] = a0; red[1][tid] = a1; red[2][tid] = a2;
    red[3][tid] = a3; red[4][tid] = a4;
    __syncthreads();
    for (int s2 = 512; s2 > 0; s2 >>= 1) {
        if (tid < s2) {
            red[0][tid] += red[0][tid + s2];
            red[1][tid] += red[1][tid + s2];
            red[2][tid] += red[2][tid + s2];
            red[3][tid] += red[3][tid + s2];
            red[4][tid] += red[4][tid + s2];
        }
        __syncthreads();
    }
    if (tid == 0) {
        out[0] = (float)(red[0][0] / (red[1][0] + 1e-8));
        out[1] = (float)(-red[2][0] / (double)NTOK);
        out[2] = (float)(-red[3][0] / (double)NTOK);
        out[3] = (float)(red[4][0] / (double)NTOK);
    }
}

extern "C" void kernel_launch(void* const* d_in, const int* in_sizes, int n_in,
                              void* d_out, int out_size, void* d_ws, size_t ws_size,
                              hipStream_t stream) {
    const float* hidden         = (const float*)d_in[0];
    const float* item_emb       = (const float*)d_in[1];
    const float* cluster_emb    = (const float*)d_in[2];
    const float* item_mask      = (const float*)d_in[3];
    const int*   targets        = (const int*)d_in[4];
    const int*   cluster_assign = (const int*)d_in[5];
    const int*   cluster_idx    = (const int*)d_in[6];
    const int*   in_cluster_id  = (const int*)d_in[7];

    float* out = (float*)d_out;
    float* ws  = (float*)d_ws;

    const size_t dummy_elems = (size_t)NTOK * NUM_ITEMS; // 67,108,864 zeros

    hs_fused<<<NFB + NCB, 512, 0, stream>>>(
        hidden, item_emb, cluster_emb, item_mask, targets,
        cluster_assign, cluster_idx, in_cluster_id, out, ws);
    hs_final<<<1, 1024, 0, stream>>>(ws, out + dummy_elems);
}